// Round 10
// baseline (269.280 us; speedup 1.0000x reference)
//
#include <hip/hip_runtime.h>
#include <hip/hip_fp16.h>
#include <hip/hip_cooperative_groups.h>
#include <math.h>

namespace cg = cooperative_groups;

#define N_NODES 100000
#define N_EDGES 1600000
#define D_FEAT  64

#define NPB     512                                // nodes per bucket (dst>>9)
#define NBC     ((N_NODES + NPB - 1) / NPB)        // 196 buckets
#define F1_WGS  256                                // cooperative build WGs
#define NV4     (N_EDGES / 4)                      // 400000 int4 edge groups
#define CHUNK_V ((NV4 + F1_WGS - 1) / F1_WGS)      // 1563 int4s per WG
#define MAXE    (CHUNK_V * 4)                      // 6252 edges per WG
#define STAGE_CAP 16384                            // bucket_csr LDS staging (64 KB)
#define CASTN   ((N_NODES * D_FEAT) / 4)

// ---- helpers ------------------------------------------------------------

__device__ __forceinline__ uint4 pack8(const float* v) {
    __half2 h0 = __floats2half2_rn(v[0], v[1]);
    __half2 h1 = __floats2half2_rn(v[2], v[3]);
    __half2 h2 = __floats2half2_rn(v[4], v[5]);
    __half2 h3 = __floats2half2_rn(v[6], v[7]);
    uint4 st;
    st.x = *(unsigned*)&h0; st.y = *(unsigned*)&h1;
    st.z = *(unsigned*)&h2; st.w = *(unsigned*)&h3;
    return st;
}

__device__ __forceinline__ void unp8(uint4 u, float* a) {
    { __half2 h = *(__half2*)&u.x; float2 f = __half22float2(h); a[0]=f.x; a[1]=f.y; }
    { __half2 h = *(__half2*)&u.y; float2 f = __half22float2(h); a[2]=f.x; a[3]=f.y; }
    { __half2 h = *(__half2*)&u.z; float2 f = __half22float2(h); a[4]=f.x; a[5]=f.y; }
    { __half2 h = *(__half2*)&u.w; float2 f = __half22float2(h); a[6]=f.x; a[7]=f.y; }
}

// block-wide exclusive scan over 256 ints (wsum: 4-int LDS scratch).
// Caller must __syncthreads() before reuse of wsum.
__device__ __forceinline__ int block_excl_scan_256(int v, int t, int* wsum) {
    int lane = t & 63, wv = t >> 6;
    int incl = v;
    #pragma unroll
    for (int m = 1; m < 64; m <<= 1) {
        int o = __shfl_up(incl, m);
        if (lane >= m) incl += o;
    }
    if (lane == 63) wsum[wv] = incl;
    __syncthreads();
    int prefix = 0;
    #pragma unroll
    for (int j = 0; j < 4; j++)
        if (j < wv) prefix += wsum[j];
    return prefix + incl - v;
}

// block-wide exclusive scan over 512 ints (used by bucket_csr).
__device__ __forceinline__ int block_excl_scan_512(int v, int t, int* wsum) {
    int lane = t & 63, wv = t >> 6;
    int incl = v;
    #pragma unroll
    for (int m = 1; m < 64; m <<= 1) {
        int o = __shfl_up(incl, m);
        if (lane >= m) incl += o;
    }
    if (lane == 63) wsum[wv] = incl;
    __syncthreads();
    int prefix = 0;
    #pragma unroll
    for (int j = 0; j < 8; j++)
        if (j < wv) prefix += wsum[j];
    return prefix + incl - v;
}

// ---- cast f32 rows -> row-major fp16 table ------------------------------

__global__ void cast_feat(const float* __restrict__ in,
                          __half* __restrict__ out) {
    int i = blockIdx.x * blockDim.x + threadIdx.x;
    if (i >= CASTN) return;
    float4 v = ((const float4*)in)[i];
    __half2 h0 = __floats2half2_rn(v.x, v.y);
    __half2 h1 = __floats2half2_rn(v.z, v.w);
    uint2 st;
    st.x = *(unsigned*)&h0;
    st.y = *(unsigned*)&h1;
    ((uint2*)out)[i] = st;
}

// ---- cooperative single-kernel coarse build -----------------------------
// Replaces hist + colscan + scan + bucketize. Each WG stages its edges in
// LDS once, grid-syncs to scan percnt/bhist, locally sorts by bucket and
// flushes contiguous bucket-runs (coalesced) into tmp1.

__global__ __launch_bounds__(256) void build_coop(
        const int4* __restrict__ src4,
        const int4* __restrict__ dst4,
        int* __restrict__ percnt,
        int* __restrict__ bhist,
        int* __restrict__ bbase_g,
        unsigned int* __restrict__ tmp1) {
    __shared__ unsigned int raw[MAXE];
    __shared__ unsigned int ord[MAXE];
    __shared__ unsigned short bkt[MAXE];
    __shared__ unsigned short bkt2[MAXE];
    __shared__ int lcnt[NBC];
    __shared__ int loff[NBC];
    __shared__ int lcur[NBC];
    __shared__ int gb[NBC];
    __shared__ int wsum[4];

    cg::grid_group grid = cg::this_grid();
    int wg = blockIdx.x, t = threadIdx.x;

    for (int i = t; i < NBC; i += 256) { lcnt[i] = 0; lcur[i] = 0; }
    __syncthreads();

    int i0 = wg * CHUNK_V;
    int i1 = min(i0 + CHUNK_V, NV4);
    int ne = (i1 - i0) * 4;

    // pass 1: stage + count (edges read from global exactly once)
    for (int i = i0 + t; i < i1; i += 256) {
        int4 d = dst4[i];
        int4 s = src4[i];
        int j = (i - i0) * 4;
        int b0 = d.x >> 9, b1 = d.y >> 9, b2 = d.z >> 9, b3 = d.w >> 9;
        raw[j + 0] = ((unsigned)s.x << 9) | (unsigned)(d.x & 511); bkt[j + 0] = (unsigned short)b0;
        raw[j + 1] = ((unsigned)s.y << 9) | (unsigned)(d.y & 511); bkt[j + 1] = (unsigned short)b1;
        raw[j + 2] = ((unsigned)s.z << 9) | (unsigned)(d.z & 511); bkt[j + 2] = (unsigned short)b2;
        raw[j + 3] = ((unsigned)s.w << 9) | (unsigned)(d.w & 511); bkt[j + 3] = (unsigned short)b3;
        atomicAdd(&lcnt[b0], 1);
        atomicAdd(&lcnt[b1], 1);
        atomicAdd(&lcnt[b2], 1);
        atomicAdd(&lcnt[b3], 1);
    }
    __syncthreads();
    for (int i = t; i < NBC; i += 256) percnt[i * F1_WGS + wg] = lcnt[i];

    grid.sync();

    // colscan: WG b scans percnt row b (exclusive over the 256 WGs)
    if (wg < NBC) {
        int v = percnt[wg * F1_WGS + t];
        int ex = block_excl_scan_256(v, t, wsum);
        percnt[wg * F1_WGS + t] = ex;
        if (t == 255) bhist[wg] = ex + v;
    }

    grid.sync();

    // bbase: every WG scans bhist locally; WG0 also writes it to global
    __syncthreads();                       // protect wsum reuse
    {
        int v = (t < NBC) ? bhist[t] : 0;
        int ex = block_excl_scan_256(v, t, wsum);
        if (t < NBC) gb[t] = ex;           // bbase[t], percnt added below
        if (wg == 0) {
            if (t < NBC) bbase_g[t] = ex;
            if (t == NBC) bbase_g[NBC] = N_EDGES;
        }
    }
    __syncthreads();
    for (int i = t; i < NBC; i += 256)
        gb[i] += percnt[i * F1_WGS + wg];  // this WG's global base per bucket

    // local scan of lcnt -> loff
    __syncthreads();                       // protect wsum reuse
    {
        int v = (t < NBC) ? lcnt[t] : 0;
        int ex = block_excl_scan_256(v, t, wsum);
        if (t < NBC) loff[t] = ex;
    }
    __syncthreads();

    // pass 2: local counting-sort into ord
    for (int j = t; j < ne; j += 256) {
        int b = bkt[j];
        int r = atomicAdd(&lcur[b], 1);
        int p = loff[b] + r;
        ord[p] = raw[j];
        bkt2[p] = (unsigned short)b;
    }
    __syncthreads();

    // flush: consecutive j within a bucket-run -> consecutive global addrs
    for (int j = t; j < ne; j += 256) {
        int b = bkt2[j];
        tmp1[gb[b] + (j - loff[b])] = ord[j];
    }
}

// ---- per-bucket node sort -> CSR (unchanged, proven) --------------------

__global__ __launch_bounds__(NPB) void bucket_csr(
        const unsigned int* __restrict__ tmp1,
        const int* __restrict__ bbase,
        int* __restrict__ offsets,
        int* __restrict__ csr_src) {
    __shared__ int cnt[NPB];
    __shared__ int off[NPB];
    __shared__ int wsum[8];
    __shared__ int stage[STAGE_CAP];
    int b = blockIdx.x, t = threadIdx.x;
    int ebase = bbase[b];
    int ecnt  = bbase[b + 1] - ebase;
    int node0 = b * NPB;

    cnt[t] = 0;
    __syncthreads();
    for (int i = t; i < ecnt; i += NPB)
        atomicAdd(&cnt[tmp1[ebase + i] & 511], 1);
    __syncthreads();

    int v = cnt[t];
    int excl = block_excl_scan_512(v, t, wsum);
    off[t] = excl;
    cnt[t] = 0;  // reuse as cursor
    if (node0 + t < N_NODES) offsets[node0 + t] = ebase + excl;
    if (b == NBC - 1 && t == 0) offsets[N_NODES] = N_EDGES;
    __syncthreads();

    if (ecnt <= STAGE_CAP) {
        for (int i = t; i < ecnt; i += NPB) {
            unsigned u = tmp1[ebase + i];
            int d = (int)(u & 511);
            int r = atomicAdd(&cnt[d], 1);
            stage[off[d] + r] = (int)(u >> 9);
        }
        __syncthreads();
        for (int i = t; i < ecnt; i += NPB)
            csr_src[ebase + i] = stage[i];
    } else {
        for (int i = t; i < ecnt; i += NPB) {
            unsigned u = tmp1[ebase + i];
            int d = (int)(u & 511);
            int r = atomicAdd(&cnt[d], 1);
            csr_src[ebase + off[d] + r] = (int)(u >> 9);
        }
    }
}

// ---- Gather passes (round-9 proven, byte-identical) ---------------------

__global__ void gather1_kernel(const __half* __restrict__ feat_h,
                               const int* __restrict__ offsets,
                               const int* __restrict__ csr,
                               __half* __restrict__ x1_h) {
    __shared__ int scsr[4][64];
    int wv = threadIdx.x >> 6;
    int node = blockIdx.x * 4 + wv;
    if (node >= N_NODES) return;
    int lane = threadIdx.x & 63;
    int g = lane >> 3;
    int fid = (lane & 7) * 8;

    int base = offsets[node];
    int deg = offsets[node + 1] - base;

    if (lane < deg) scsr[wv][lane] = csr[base + lane];
    __builtin_amdgcn_wave_barrier();

    __half2 h0 = __float2half2_rn(0.f), h1 = h0, h2 = h0, h3 = h0;
    int dmax = min(deg, 64);
    for (int j = g; j < dmax; j += 8) {
        int s = scsr[wv][j];
        uint4 u = *(const uint4*)(feat_h + ((size_t)s << 6) + fid);
        h0 = __hadd2(h0, *(__half2*)&u.x);
        h1 = __hadd2(h1, *(__half2*)&u.y);
        h2 = __hadd2(h2, *(__half2*)&u.z);
        h3 = __hadd2(h3, *(__half2*)&u.w);
    }
    for (int j = 64 + g; j < deg; j += 8) {
        int s = csr[base + j];
        uint4 u = *(const uint4*)(feat_h + ((size_t)s << 6) + fid);
        h0 = __hadd2(h0, *(__half2*)&u.x);
        h1 = __hadd2(h1, *(__half2*)&u.y);
        h2 = __hadd2(h2, *(__half2*)&u.z);
        h3 = __hadd2(h3, *(__half2*)&u.w);
    }
    float acc[8];
    { float2 f = __half22float2(h0); acc[0]=f.x; acc[1]=f.y; }
    { float2 f = __half22float2(h1); acc[2]=f.x; acc[3]=f.y; }
    { float2 f = __half22float2(h2); acc[4]=f.x; acc[5]=f.y; }
    { float2 f = __half22float2(h3); acc[6]=f.x; acc[7]=f.y; }
    #pragma unroll
    for (int m = 8; m < 64; m <<= 1)
        #pragma unroll
        for (int t = 0; t < 8; t++)
            acc[t] += __shfl_xor(acc[t], m);

    if (lane < 8) {
        float inv = (deg > 0) ? 1.0f / (float)deg : 0.0f;
        float r[8];
        #pragma unroll
        for (int t = 0; t < 8; t++) r[t] = acc[t] * inv;
        *(uint4*)(x1_h + ((size_t)node << 6) + fid) = pack8(r);
    }
}

__global__ void gather2_finalize_kernel(const __half* __restrict__ x1_h,
                                        const int* __restrict__ offsets,
                                        const int* __restrict__ csr,
                                        float* __restrict__ out) {
    __shared__ int scsr[4][64];
    int wv = threadIdx.x >> 6;
    int node = blockIdx.x * 4 + wv;
    if (node >= N_NODES) return;
    int lane = threadIdx.x & 63;
    int g = lane >> 3;
    int fid = (lane & 7) * 8;

    int base = offsets[node];
    int deg = offsets[node + 1] - base;

    if (lane < deg) scsr[wv][lane] = csr[base + lane];
    __builtin_amdgcn_wave_barrier();

    __half2 h0 = __float2half2_rn(0.f), h1 = h0, h2 = h0, h3 = h0;
    int dmax = min(deg, 64);
    for (int j = g; j < dmax; j += 8) {
        int s = scsr[wv][j];
        uint4 u = *(const uint4*)(x1_h + ((size_t)s << 6) + fid);
        h0 = __hadd2(h0, *(__half2*)&u.x);
        h1 = __hadd2(h1, *(__half2*)&u.y);
        h2 = __hadd2(h2, *(__half2*)&u.z);
        h3 = __hadd2(h3, *(__half2*)&u.w);
    }
    for (int j = 64 + g; j < deg; j += 8) {
        int s = csr[base + j];
        uint4 u = *(const uint4*)(x1_h + ((size_t)s << 6) + fid);
        h0 = __hadd2(h0, *(__half2*)&u.x);
        h1 = __hadd2(h1, *(__half2*)&u.y);
        h2 = __hadd2(h2, *(__half2*)&u.z);
        h3 = __hadd2(h3, *(__half2*)&u.w);
    }
    float acc[8];
    { float2 f = __half22float2(h0); acc[0]=f.x; acc[1]=f.y; }
    { float2 f = __half22float2(h1); acc[2]=f.x; acc[3]=f.y; }
    { float2 f = __half22float2(h2); acc[4]=f.x; acc[5]=f.y; }
    { float2 f = __half22float2(h3); acc[6]=f.x; acc[7]=f.y; }
    #pragma unroll
    for (int m = 8; m < 64; m <<= 1)
        #pragma unroll
        for (int t = 0; t < 8; t++)
            acc[t] += __shfl_xor(acc[t], m);

    float inv = (deg > 0) ? 1.0f / (float)deg : 0.0f;
    float b[8], a[8];
    #pragma unroll
    for (int t = 0; t < 8; t++) b[t] = acc[t] * inv;

    uint4 ua = *(const uint4*)(x1_h + ((size_t)node << 6) + fid);
    unp8(ua, a);

    float dot = 0.f, nn1 = 0.f, nn2 = 0.f;
    #pragma unroll
    for (int t = 0; t < 8; t++) {
        dot += a[t] * b[t];
        nn1 += a[t] * a[t];
        nn2 += b[t] * b[t];
    }
    #pragma unroll
    for (int m = 1; m < 64; m <<= 1) {
        dot += __shfl_xor(dot, m);
        nn1 += __shfl_xor(nn1, m);
        nn2 += __shfl_xor(nn2, m);
    }
    dot *= 0.125f; nn1 *= 0.125f; nn2 *= 0.125f;  // 8 groups duplicate

    float w = dot / fmaxf(sqrtf(nn1) * sqrtf(nn2), 1e-8f);
    if (lane < 8) {
        float omw = 1.0f - w;
        float4 r0, r1;
        r0.x = w*b[0] + omw*a[0]; r0.y = w*b[1] + omw*a[1];
        r0.z = w*b[2] + omw*a[2]; r0.w = w*b[3] + omw*a[3];
        r1.x = w*b[4] + omw*a[4]; r1.y = w*b[5] + omw*a[5];
        r1.z = w*b[6] + omw*a[6]; r1.w = w*b[7] + omw*a[7];
        float* po = out + ((size_t)node << 6) + fid;
        *(float4*)po = r0;
        *(float4*)(po + 4) = r1;
    }
}

// ---- launch -------------------------------------------------------------

extern "C" void kernel_launch(void* const* d_in, const int* in_sizes, int n_in,
                              void* d_out, int out_size, void* d_ws, size_t ws_size,
                              hipStream_t stream) {
    const float* feat = (const float*)d_in[0];
    const int*   eidx = (const int*)d_in[1];
    const int4*  src4 = (const int4*)eidx;
    const int4*  dst4 = (const int4*)(eidx + N_EDGES);

    __half*       feat_h  = (__half*)d_ws;                          // 12.8 MB
    __half*       x1_h    = feat_h + (size_t)N_NODES * D_FEAT;      // 12.8 MB
    unsigned int* tmp1    = (unsigned int*)(x1_h + (size_t)N_NODES * D_FEAT); // 6.4 MB
    int*          csr_src = (int*)(tmp1 + N_EDGES);                 // 6.4 MB
    int*          offsets = csr_src + N_EDGES;                      // 100001
    int*          percnt  = offsets + (N_NODES + 1);                // NBC*F1_WGS
    int*          bhist   = percnt + NBC * F1_WGS;                  // NBC
    int*          bbase   = bhist + NBC;                            // NBC+1
    float*        out     = (float*)d_out;

    const int BLK = 256;
    cast_feat<<<(CASTN + BLK - 1) / BLK, BLK, 0, stream>>>(feat, feat_h);

    {
        void* args[] = { (void*)&src4, (void*)&dst4, (void*)&percnt,
                         (void*)&bhist, (void*)&bbase, (void*)&tmp1 };
        hipLaunchCooperativeKernel((const void*)build_coop,
                                   dim3(F1_WGS), dim3(256), args, 0, stream);
    }

    bucket_csr<<<NBC, NPB, 0, stream>>>(tmp1, bbase, offsets, csr_src);

    int nblocks = (N_NODES + 3) / 4;
    gather1_kernel<<<nblocks, BLK, 0, stream>>>(feat_h, offsets, csr_src, x1_h);
    gather2_finalize_kernel<<<nblocks, BLK, 0, stream>>>(x1_h, offsets, csr_src, out);
}

// Round 11
// 200.639 us; speedup vs baseline: 1.3421x; 1.3421x over previous
//
#include <hip/hip_runtime.h>
#include <hip/hip_fp16.h>
#include <math.h>

#define N_NODES 100000
#define N_EDGES 1600000
#define D_FEAT  64

#define NPB     256                                // nodes per bucket (dst>>8)
#define NBC     ((N_NODES + NPB - 1) / NPB)        // 391 buckets
#define F1_WGS  512                                // chunking WGs for hist/bucketize
#define NV4     (N_EDGES / 4)                      // 400000 int4 edge groups
#define CHUNK_V ((NV4 + F1_WGS - 1) / F1_WGS)      // 782 int4s per WG
#define STAGE_CAP 8192                             // bucket_csr LDS staging (32 KB)
#define CASTN   ((N_NODES * D_FEAT) / 4)           // 1.6M float4 groups
#define CAST_BLOCKS ((CASTN + 255) / 256)          // 6250

// ---- helpers ------------------------------------------------------------

__device__ __forceinline__ uint4 pack8(const float* v) {
    __half2 h0 = __floats2half2_rn(v[0], v[1]);
    __half2 h1 = __floats2half2_rn(v[2], v[3]);
    __half2 h2 = __floats2half2_rn(v[4], v[5]);
    __half2 h3 = __floats2half2_rn(v[6], v[7]);
    uint4 st;
    st.x = *(unsigned*)&h0; st.y = *(unsigned*)&h1;
    st.z = *(unsigned*)&h2; st.w = *(unsigned*)&h3;
    return st;
}

__device__ __forceinline__ void unp8(uint4 u, float* a) {
    { __half2 h = *(__half2*)&u.x; float2 f = __half22float2(h); a[0]=f.x; a[1]=f.y; }
    { __half2 h = *(__half2*)&u.y; float2 f = __half22float2(h); a[2]=f.x; a[3]=f.y; }
    { __half2 h = *(__half2*)&u.z; float2 f = __half22float2(h); a[4]=f.x; a[5]=f.y; }
    { __half2 h = *(__half2*)&u.w; float2 f = __half22float2(h); a[6]=f.x; a[7]=f.y; }
}

// block-wide exclusive scan over 512 ints (3-ish barriers; wsum = 8-int LDS).
// Contains one __syncthreads after the wsum store.
__device__ __forceinline__ int block_excl_scan_512(int v, int t, int* wsum) {
    int lane = t & 63, wv = t >> 6;
    int incl = v;
    #pragma unroll
    for (int m = 1; m < 64; m <<= 1) {
        int o = __shfl_up(incl, m);
        if (lane >= m) incl += o;
    }
    if (lane == 63) wsum[wv] = incl;
    __syncthreads();
    int prefix = 0;
    #pragma unroll
    for (int j = 0; j < 8; j++)
        if (j < wv) prefix += wsum[j];
    return prefix + incl - v;
}

// ---- fused cast + coarse histogram --------------------------------------
// blocks [0, F1_WGS): histogram chunk; blocks [F1_WGS, ...): cast.

__global__ void cast_and_hist(const float* __restrict__ feat,
                              __half* __restrict__ feat_h,
                              const int4* __restrict__ dst4,
                              int* __restrict__ percnt) {
    if (blockIdx.x >= F1_WGS) {
        int i = (blockIdx.x - F1_WGS) * 256 + threadIdx.x;
        if (i < CASTN) {
            float4 v = ((const float4*)feat)[i];
            __half2 h0 = __floats2half2_rn(v.x, v.y);
            __half2 h1 = __floats2half2_rn(v.z, v.w);
            uint2 st;
            st.x = *(unsigned*)&h0;
            st.y = *(unsigned*)&h1;
            ((uint2*)feat_h)[i] = st;
        }
        return;
    }
    __shared__ int cnt[NBC];
    for (int i = threadIdx.x; i < NBC; i += blockDim.x) cnt[i] = 0;
    __syncthreads();
    int i0 = blockIdx.x * CHUNK_V;
    int i1 = min(i0 + CHUNK_V, NV4);
    for (int i = i0 + threadIdx.x; i < i1; i += blockDim.x) {
        int4 d = dst4[i];
        atomicAdd(&cnt[d.x >> 8], 1);
        atomicAdd(&cnt[d.y >> 8], 1);
        atomicAdd(&cnt[d.z >> 8], 1);
        atomicAdd(&cnt[d.w >> 8], 1);
    }
    __syncthreads();
    for (int i = threadIdx.x; i < NBC; i += blockDim.x)
        percnt[i * F1_WGS + blockIdx.x] = cnt[i];
}

// ---- CSR build ----------------------------------------------------------

// Per-bucket exclusive scan across the F1_WGS workgroups; totals -> bhist.
__global__ __launch_bounds__(F1_WGS) void bucket_colscan(
        int* __restrict__ percnt, int* __restrict__ bhist) {
    __shared__ int wsum[8];
    int b = blockIdx.x, t = threadIdx.x;
    int v = percnt[b * F1_WGS + t];
    int excl = block_excl_scan_512(v, t, wsum);
    percnt[b * F1_WGS + t] = excl;
    if (t == F1_WGS - 1) bhist[b] = excl + v;
}

// Scatter edges into bucket-contiguous tmp1, packed (src<<8)|(dst&255).
// Computes bbase locally from bhist (no bucket_scan kernel).
__global__ __launch_bounds__(F1_WGS) void bucketize(
        const int4* __restrict__ src4,
        const int4* __restrict__ dst4,
        const int* __restrict__ bhist,
        const int* __restrict__ percnt,
        unsigned int* __restrict__ tmp1) {
    __shared__ int base[NBC];
    __shared__ int cur[NBC];
    __shared__ int wsum[8];
    int wg = blockIdx.x, t = threadIdx.x;
    // local scan of bhist -> bbase
    int v = (t < NBC) ? bhist[t] : 0;
    int excl = block_excl_scan_512(v, t, wsum);
    if (t < NBC) {
        base[t] = excl + percnt[t * F1_WGS + wg];
        cur[t] = 0;
    }
    __syncthreads();
    int i0 = wg * CHUNK_V;
    int i1 = min(i0 + CHUNK_V, NV4);
    for (int i = i0 + t; i < i1; i += F1_WGS) {
        int4 d = dst4[i];
        int4 s = src4[i];
        {
            int b = d.x >> 8; int r = atomicAdd(&cur[b], 1);
            tmp1[base[b] + r] = ((unsigned)s.x << 8) | (unsigned)(d.x & 255);
        }
        {
            int b = d.y >> 8; int r = atomicAdd(&cur[b], 1);
            tmp1[base[b] + r] = ((unsigned)s.y << 8) | (unsigned)(d.y & 255);
        }
        {
            int b = d.z >> 8; int r = atomicAdd(&cur[b], 1);
            tmp1[base[b] + r] = ((unsigned)s.z << 8) | (unsigned)(d.z & 255);
        }
        {
            int b = d.w >> 8; int r = atomicAdd(&cur[b], 1);
            tmp1[base[b] + r] = ((unsigned)s.w << 8) | (unsigned)(d.w & 255);
        }
    }
}

// One 512-thread WG per 256-node bucket: ebase/ecnt from local bhist scan
// (thread b's exclusive prefix IS bbase[b]); LDS node histogram + scan ->
// offsets (coalesced); LDS-staged counting sort -> csr_src coalesced.
__global__ __launch_bounds__(512) void bucket_csr(
        const unsigned int* __restrict__ tmp1,
        const int* __restrict__ bhist,
        int* __restrict__ offsets,
        int* __restrict__ csr_src) {
    __shared__ int cnt[NPB];
    __shared__ int off[NPB];
    __shared__ int wsum[8];
    __shared__ int stage[STAGE_CAP];
    __shared__ int sEbase, sEcnt;
    int b = blockIdx.x, t = threadIdx.x;

    {   // bbase[b] = exclusive prefix of bhist at index b
        int v = (t < NBC) ? bhist[t] : 0;
        int ex = block_excl_scan_512(v, t, wsum);
        if (t == b) { sEbase = ex; sEcnt = v; }
    }
    if (t < NPB) cnt[t] = 0;
    __syncthreads();
    int ebase = sEbase;
    int ecnt  = sEcnt;
    int node0 = b * NPB;

    for (int i = t; i < ecnt; i += 512)
        atomicAdd(&cnt[tmp1[ebase + i] & 255], 1);
    __syncthreads();

    int v = (t < NPB) ? cnt[t] : 0;
    int excl = block_excl_scan_512(v, t, wsum);
    if (t < NPB) {
        off[t] = excl;
        cnt[t] = 0;  // reuse as cursor
        if (node0 + t < N_NODES) offsets[node0 + t] = ebase + excl;
    }
    if (b == NBC - 1 && t == 0) offsets[N_NODES] = N_EDGES;
    __syncthreads();

    if (ecnt <= STAGE_CAP) {
        for (int i = t; i < ecnt; i += 512) {
            unsigned u = tmp1[ebase + i];
            int d = (int)(u & 255);
            int r = atomicAdd(&cnt[d], 1);
            stage[off[d] + r] = (int)(u >> 8);
        }
        __syncthreads();
        for (int i = t; i < ecnt; i += 512)
            csr_src[ebase + i] = stage[i];
    } else {
        for (int i = t; i < ecnt; i += 512) {
            unsigned u = tmp1[ebase + i];
            int d = (int)(u & 255);
            int r = atomicAdd(&cnt[d], 1);
            csr_src[ebase + off[d] + r] = (int)(u >> 8);
        }
    }
}

// ---- Gather passes (round-9 proven, byte-identical) ---------------------

__global__ void gather1_kernel(const __half* __restrict__ feat_h,
                               const int* __restrict__ offsets,
                               const int* __restrict__ csr,
                               __half* __restrict__ x1_h) {
    __shared__ int scsr[4][64];
    int wv = threadIdx.x >> 6;
    int node = blockIdx.x * 4 + wv;
    if (node >= N_NODES) return;
    int lane = threadIdx.x & 63;
    int g = lane >> 3;
    int fid = (lane & 7) * 8;

    int base = offsets[node];
    int deg = offsets[node + 1] - base;

    if (lane < deg) scsr[wv][lane] = csr[base + lane];
    __builtin_amdgcn_wave_barrier();

    __half2 h0 = __float2half2_rn(0.f), h1 = h0, h2 = h0, h3 = h0;
    int dmax = min(deg, 64);
    for (int j = g; j < dmax; j += 8) {
        int s = scsr[wv][j];
        uint4 u = *(const uint4*)(feat_h + ((size_t)s << 6) + fid);
        h0 = __hadd2(h0, *(__half2*)&u.x);
        h1 = __hadd2(h1, *(__half2*)&u.y);
        h2 = __hadd2(h2, *(__half2*)&u.z);
        h3 = __hadd2(h3, *(__half2*)&u.w);
    }
    for (int j = 64 + g; j < deg; j += 8) {
        int s = csr[base + j];
        uint4 u = *(const uint4*)(feat_h + ((size_t)s << 6) + fid);
        h0 = __hadd2(h0, *(__half2*)&u.x);
        h1 = __hadd2(h1, *(__half2*)&u.y);
        h2 = __hadd2(h2, *(__half2*)&u.z);
        h3 = __hadd2(h3, *(__half2*)&u.w);
    }
    float acc[8];
    { float2 f = __half22float2(h0); acc[0]=f.x; acc[1]=f.y; }
    { float2 f = __half22float2(h1); acc[2]=f.x; acc[3]=f.y; }
    { float2 f = __half22float2(h2); acc[4]=f.x; acc[5]=f.y; }
    { float2 f = __half22float2(h3); acc[6]=f.x; acc[7]=f.y; }
    #pragma unroll
    for (int m = 8; m < 64; m <<= 1)
        #pragma unroll
        for (int t = 0; t < 8; t++)
            acc[t] += __shfl_xor(acc[t], m);

    if (lane < 8) {
        float inv = (deg > 0) ? 1.0f / (float)deg : 0.0f;
        float r[8];
        #pragma unroll
        for (int t = 0; t < 8; t++) r[t] = acc[t] * inv;
        *(uint4*)(x1_h + ((size_t)node << 6) + fid) = pack8(r);
    }
}

__global__ void gather2_finalize_kernel(const __half* __restrict__ x1_h,
                                        const int* __restrict__ offsets,
                                        const int* __restrict__ csr,
                                        float* __restrict__ out) {
    __shared__ int scsr[4][64];
    int wv = threadIdx.x >> 6;
    int node = blockIdx.x * 4 + wv;
    if (node >= N_NODES) return;
    int lane = threadIdx.x & 63;
    int g = lane >> 3;
    int fid = (lane & 7) * 8;

    int base = offsets[node];
    int deg = offsets[node + 1] - base;

    if (lane < deg) scsr[wv][lane] = csr[base + lane];
    __builtin_amdgcn_wave_barrier();

    __half2 h0 = __float2half2_rn(0.f), h1 = h0, h2 = h0, h3 = h0;
    int dmax = min(deg, 64);
    for (int j = g; j < dmax; j += 8) {
        int s = scsr[wv][j];
        uint4 u = *(const uint4*)(x1_h + ((size_t)s << 6) + fid);
        h0 = __hadd2(h0, *(__half2*)&u.x);
        h1 = __hadd2(h1, *(__half2*)&u.y);
        h2 = __hadd2(h2, *(__half2*)&u.z);
        h3 = __hadd2(h3, *(__half2*)&u.w);
    }
    for (int j = 64 + g; j < deg; j += 8) {
        int s = csr[base + j];
        uint4 u = *(const uint4*)(x1_h + ((size_t)s << 6) + fid);
        h0 = __hadd2(h0, *(__half2*)&u.x);
        h1 = __hadd2(h1, *(__half2*)&u.y);
        h2 = __hadd2(h2, *(__half2*)&u.z);
        h3 = __hadd2(h3, *(__half2*)&u.w);
    }
    float acc[8];
    { float2 f = __half22float2(h0); acc[0]=f.x; acc[1]=f.y; }
    { float2 f = __half22float2(h1); acc[2]=f.x; acc[3]=f.y; }
    { float2 f = __half22float2(h2); acc[4]=f.x; acc[5]=f.y; }
    { float2 f = __half22float2(h3); acc[6]=f.x; acc[7]=f.y; }
    #pragma unroll
    for (int m = 8; m < 64; m <<= 1)
        #pragma unroll
        for (int t = 0; t < 8; t++)
            acc[t] += __shfl_xor(acc[t], m);

    float inv = (deg > 0) ? 1.0f / (float)deg : 0.0f;
    float b[8], a[8];
    #pragma unroll
    for (int t = 0; t < 8; t++) b[t] = acc[t] * inv;

    uint4 ua = *(const uint4*)(x1_h + ((size_t)node << 6) + fid);
    unp8(ua, a);

    float dot = 0.f, nn1 = 0.f, nn2 = 0.f;
    #pragma unroll
    for (int t = 0; t < 8; t++) {
        dot += a[t] * b[t];
        nn1 += a[t] * a[t];
        nn2 += b[t] * b[t];
    }
    #pragma unroll
    for (int m = 1; m < 64; m <<= 1) {
        dot += __shfl_xor(dot, m);
        nn1 += __shfl_xor(nn1, m);
        nn2 += __shfl_xor(nn2, m);
    }
    dot *= 0.125f; nn1 *= 0.125f; nn2 *= 0.125f;  // 8 groups duplicate

    float w = dot / fmaxf(sqrtf(nn1) * sqrtf(nn2), 1e-8f);
    if (lane < 8) {
        float omw = 1.0f - w;
        float4 r0, r1;
        r0.x = w*b[0] + omw*a[0]; r0.y = w*b[1] + omw*a[1];
        r0.z = w*b[2] + omw*a[2]; r0.w = w*b[3] + omw*a[3];
        r1.x = w*b[4] + omw*a[4]; r1.y = w*b[5] + omw*a[5];
        r1.z = w*b[6] + omw*a[6]; r1.w = w*b[7] + omw*a[7];
        float* po = out + ((size_t)node << 6) + fid;
        *(float4*)po = r0;
        *(float4*)(po + 4) = r1;
    }
}

// ---- launch -------------------------------------------------------------

extern "C" void kernel_launch(void* const* d_in, const int* in_sizes, int n_in,
                              void* d_out, int out_size, void* d_ws, size_t ws_size,
                              hipStream_t stream) {
    const float* feat = (const float*)d_in[0];
    const int*   eidx = (const int*)d_in[1];
    const int4*  src4 = (const int4*)eidx;
    const int4*  dst4 = (const int4*)(eidx + N_EDGES);

    __half*       feat_h  = (__half*)d_ws;                          // 12.8 MB
    __half*       x1_h    = feat_h + (size_t)N_NODES * D_FEAT;      // 12.8 MB
    unsigned int* tmp1    = (unsigned int*)(x1_h + (size_t)N_NODES * D_FEAT); // 6.4 MB
    int*          csr_src = (int*)(tmp1 + N_EDGES);                 // 6.4 MB
    int*          offsets = csr_src + N_EDGES;                      // 100001
    int*          percnt  = offsets + (N_NODES + 1);                // NBC*F1_WGS
    int*          bhist   = percnt + NBC * F1_WGS;                  // NBC
    float*        out     = (float*)d_out;

    cast_and_hist <<<F1_WGS + CAST_BLOCKS, 256, 0, stream>>>(feat, feat_h, dst4, percnt);
    bucket_colscan<<<NBC, F1_WGS, 0, stream>>>(percnt, bhist);
    bucketize     <<<F1_WGS, F1_WGS, 0, stream>>>(src4, dst4, bhist, percnt, tmp1);
    bucket_csr    <<<NBC, 512, 0, stream>>>(tmp1, bhist, offsets, csr_src);

    const int BLK = 256;
    int nblocks = (N_NODES + 3) / 4;
    gather1_kernel<<<nblocks, BLK, 0, stream>>>(feat_h, offsets, csr_src, x1_h);
    gather2_finalize_kernel<<<nblocks, BLK, 0, stream>>>(x1_h, offsets, csr_src, out);
}